// Round 5
// baseline (223.385 us; speedup 1.0000x reference)
//
#include <hip/hip_runtime.h>
#include <cstddef>
#include <cstdint>

#define IN_F 512
#define OUT_F 128
#define NREL 10
#define MAXBINS 16000
#define CCHUNK 16384

typedef __attribute__((ext_vector_type(8))) short short8;
typedef __attribute__((ext_vector_type(4))) float f32x4;

static const int kNSrc[NREL]   = {8000,16000,8000,16000,8000,4000,8000,4000,16000,4000};
static const int kNDst[NREL]   = {8000,16000,16000,8000,4000,8000,4000,8000,4000,16000};
static const int kNEdges[NREL] = {200000,800000,400000,400000,100000,100000,100000,100000,150000,150000};
static const int kRelSrcType[NREL] = {0,1,0,1,0,2,0,3,1,2};
static const int kNNodes[4] = {8000,16000,4000,4000};
static const size_t kOutOff[4] = {0, 8000ull*OUT_F, 24000ull*OUT_F, 28000ull*OUT_F};
static const int kDstRels[4][4] = {{0,3,5,7},{1,2,9,-1},{4,8,-1,-1},{6,-1,-1,-1}};
static const int kNDstRels[4] = {4,3,2,1};

__device__ __forceinline__ unsigned short f2bf(float f) {
  union { float f; unsigned u; } v; v.f = f;
  unsigned r = v.u + 0x7fffu + ((v.u >> 16) & 1u);
  return (unsigned short)(r >> 16);
}
__device__ __forceinline__ float bf2f(unsigned short b) {
  union { unsigned u; float f; } v; v.u = ((unsigned)b) << 16;
  return v.f;
}
__device__ __forceinline__ void add8(float* a, uint4 u) {
  union { unsigned u; float f; } t;
  t.u = u.x << 16;        a[0] += t.f;
  t.u = u.x & 0xffff0000; a[1] += t.f;
  t.u = u.y << 16;        a[2] += t.f;
  t.u = u.y & 0xffff0000; a[3] += t.f;
  t.u = u.z << 16;        a[4] += t.f;
  t.u = u.z & 0xffff0000; a[5] += t.f;
  t.u = u.w << 16;        a[6] += t.f;
  t.u = u.w & 0xffff0000; a[7] += t.f;
}

// ---------------- per-chunk LDS histogram -> coalesced u16 H rows ---------------------
struct CountJob { const int* idx; unsigned short* H; int n_edges; int nbins; };
struct CountParams { CountJob j[2 * NREL]; };

__global__ __launch_bounds__(512) void k_count(CountParams p) {
  CountJob J = p.j[blockIdx.y];
  const int e0 = blockIdx.x * CCHUNK;
  if (e0 >= J.n_edges) return;
  __shared__ int lb[MAXBINS];
  const int t = threadIdx.x;
  for (int d = t; d < J.nbins; d += 512) lb[d] = 0;
  __syncthreads();
  const int eend = (e0 + CCHUNK < J.n_edges) ? e0 + CCHUNK : J.n_edges;
  for (int e = e0 + t; e < eend; e += 512) atomicAdd(&lb[J.idx[e]], 1);
  __syncthreads();
  unsigned short* Hrow = J.H + (size_t)blockIdx.x * J.nbins;
  for (int d = t; d < J.nbins; d += 512) Hrow[d] = (unsigned short)lb[d];
}

// ---------------- column-sum of H -> totals, coalesced --------------------------------
struct SumJob { const unsigned short* H; int* tot; int nbins; int nblocks; };
struct SumParams { SumJob j[2 * NREL]; };

__global__ __launch_bounds__(256) void k_sum(SumParams p) {
  SumJob J = p.j[blockIdx.y];
  const int bin = blockIdx.x * 256 + threadIdx.x;
  if (bin >= J.nbins) return;
  int s = 0;
  for (int b = 0; b < J.nblocks; ++b) s += J.H[(size_t)b * J.nbins + bin];
  J.tot[bin] = s;
}

// ---------------- exclusive scan (one 512-thread block per relation, n<=16384) -------
struct ScanRel { const int* tot; int* rowstart; int n; };
struct ScanParams { ScanRel r[NREL]; };

__global__ __launch_bounds__(512) void k_scan(ScanParams p) {
  ScanRel R = p.r[blockIdx.x];
  const int t = threadIdx.x;
  const int lane = t & 63, wv = t >> 6;
  const int base = t * 32;
  int v[32];
  int s = 0;
#pragma unroll
  for (int i = 0; i < 32; ++i) {
    int e = base + i;
    int x = (e < R.n) ? R.tot[e] : 0;
    v[i] = s; s += x;
  }
  int inc = s;
#pragma unroll
  for (int off = 1; off < 64; off <<= 1) {
    int u = __shfl_up(inc, off);
    if (lane >= off) inc += u;
  }
  __shared__ int wsum[8];
  if (lane == 63) wsum[wv] = inc;
  __syncthreads();
  int carry = 0, total = 0;
#pragma unroll
  for (int w = 0; w < 8; ++w) {
    int x = wsum[w];
    if (w < wv) carry += x;
    total += x;
  }
  const int tb = carry + (inc - s);
#pragma unroll
  for (int i = 0; i < 32; ++i) {
    int e = base + i;
    if (e < R.n) R.rowstart[e] = tb + v[i];
  }
  if (t == 0) R.rowstart[R.n] = total;
}

// ---------------- per-bin exclusive prefix over chunk-blocks (in place, u16) ---------
struct BasesJob { unsigned short* H; int nbins; int nblocks; };
struct BasesParams { BasesJob j[NREL]; };

__global__ __launch_bounds__(256) void k_bases(BasesParams p) {
  BasesJob J = p.j[blockIdx.y];
  const int bin = blockIdx.x * 256 + threadIdx.x;
  if (bin >= J.nbins) return;
  int run = 0;
  for (int b = 0; b < J.nblocks; ++b) {
    const size_t o = (size_t)b * J.nbins + bin;
    const int c = J.H[o];
    J.H[o] = (unsigned short)run;
    run += c;
  }
}

// ---------------- place edges via LDS cursors (no global atomics, u16 csr) -----------
struct PlaceJob { const int* src; const int* dst; const unsigned short* Hpre; const int* rowstart;
                  unsigned short* csr; int n_edges; int nbins; };
struct PlaceParams { PlaceJob j[NREL]; };

__global__ __launch_bounds__(512) void k_place(PlaceParams p) {
  PlaceJob J = p.j[blockIdx.y];
  const int e0 = blockIdx.x * CCHUNK;
  if (e0 >= J.n_edges) return;
  __shared__ int lb[MAXBINS];
  const int t = threadIdx.x;
  const unsigned short* Hrow = J.Hpre + (size_t)blockIdx.x * J.nbins;
  for (int d = t; d < J.nbins; d += 512) lb[d] = J.rowstart[d] + (int)Hrow[d];
  __syncthreads();
  const int eend = (e0 + CCHUNK < J.n_edges) ? e0 + CCHUNK : J.n_edges;
  for (int e = e0 + t; e < eend; e += 512) {
    const int d = J.dst[e];
    const int pos = atomicAdd(&lb[d], 1);
    J.csr[pos] = (unsigned short)J.src[e];
  }
}

// ---------------- W -> W^T bf16 ----------------
struct WtParams { const float* W[NREL]; unsigned short* WT[NREL]; };

__global__ __launch_bounds__(256) void k_wt(WtParams p) {
  const int r = blockIdx.y;
  const int g = blockIdx.x * 256 + threadIdx.x;  // 0..16383
  const int k = g >> 5;
  const int n0 = (g & 31) * 4;
  const float4 w = *(const float4*)(p.W[r] + (size_t)k * OUT_F + n0);
  unsigned short* WT = p.WT[r];
  WT[(size_t)(n0 + 0) * IN_F + k] = f2bf(w.x);
  WT[(size_t)(n0 + 1) * IN_F + k] = f2bf(w.y);
  WT[(size_t)(n0 + 2) * IN_F + k] = f2bf(w.z);
  WT[(size_t)(n0 + 3) * IN_F + k] = f2bf(w.w);
}

// ---------------- y_r = (h @ W_r) * deg_out^-1/2, bf16 MFMA ----------------
// grid: (rel, rowtile) so same-rowtile blocks (sharing h rows) dispatch adjacently.
struct GemmRel { const float* h; const unsigned short* WT; unsigned short* y; const int* deg_out; int n_src; };
struct GemmParams { GemmRel r[NREL]; };

__global__ __launch_bounds__(256) void k_gemm(GemmParams p) {
  GemmRel R = p.r[blockIdx.x];
  const int m0 = blockIdx.y * 128;
  if (m0 >= R.n_src) return;
  __shared__ unsigned short As[128][40];  // [m][k], padded
  __shared__ unsigned short Bs[128][40];  // [n][k]
  const int t = threadIdx.x;
  const int lane = t & 63, wid = t >> 6;
  const int wm = (wid >> 1) * 64, wn = (wid & 1) * 64;
  const int l16 = lane & 15, lk = (lane >> 4) * 8;
  const int arow = t >> 1;            // 0..127
  const int akoff = (t & 1) * 16;     // 0 or 16
  const int grA = m0 + arow;
  const bool avalid = grA < R.n_src;
  const float* hrow = R.h + (size_t)grA * IN_F;
  const unsigned short* wrow = R.WT + (size_t)arow * IN_F;

  f32x4 acc[4][4];
#pragma unroll
  for (int i = 0; i < 4; ++i)
#pragma unroll
    for (int j = 0; j < 4; ++j) acc[i][j] = (f32x4){0.f, 0.f, 0.f, 0.f};

  for (int k0 = 0; k0 < IN_F; k0 += 32) {
    float4 a0, a1, a2, a3;
    if (avalid) {
      a0 = *(const float4*)(hrow + k0 + akoff);
      a1 = *(const float4*)(hrow + k0 + akoff + 4);
      a2 = *(const float4*)(hrow + k0 + akoff + 8);
      a3 = *(const float4*)(hrow + k0 + akoff + 12);
    } else {
      a0 = a1 = a2 = a3 = make_float4(0.f, 0.f, 0.f, 0.f);
    }
    uint4 bv0 = *(const uint4*)(wrow + k0 + akoff);
    uint4 bv1 = *(const uint4*)(wrow + k0 + akoff + 8);

    uint4 A0, A1;
    A0.x = (unsigned)f2bf(a0.x) | ((unsigned)f2bf(a0.y) << 16);
    A0.y = (unsigned)f2bf(a0.z) | ((unsigned)f2bf(a0.w) << 16);
    A0.z = (unsigned)f2bf(a1.x) | ((unsigned)f2bf(a1.y) << 16);
    A0.w = (unsigned)f2bf(a1.z) | ((unsigned)f2bf(a1.w) << 16);
    A1.x = (unsigned)f2bf(a2.x) | ((unsigned)f2bf(a2.y) << 16);
    A1.y = (unsigned)f2bf(a2.z) | ((unsigned)f2bf(a2.w) << 16);
    A1.z = (unsigned)f2bf(a3.x) | ((unsigned)f2bf(a3.y) << 16);
    A1.w = (unsigned)f2bf(a3.z) | ((unsigned)f2bf(a3.w) << 16);

    __syncthreads();
    *(uint4*)&As[arow][akoff] = A0;
    *(uint4*)&As[arow][akoff + 8] = A1;
    *(uint4*)&Bs[arow][akoff] = bv0;
    *(uint4*)&Bs[arow][akoff + 8] = bv1;
    __syncthreads();

    short8 af[4], bfr[4];
#pragma unroll
    for (int f = 0; f < 4; ++f) af[f] = *(const short8*)&As[wm + f * 16 + l16][lk];
#pragma unroll
    for (int f = 0; f < 4; ++f) bfr[f] = *(const short8*)&Bs[wn + f * 16 + l16][lk];
#pragma unroll
    for (int i = 0; i < 4; ++i)
#pragma unroll
      for (int j = 0; j < 4; ++j)
        acc[i][j] = __builtin_amdgcn_mfma_f32_16x16x32_bf16(af[i], bfr[j], acc[i][j], 0, 0, 0);
  }

  const int r4 = (lane >> 4) * 4;  // C/D: col=lane&15, row=(lane>>4)*4+q
#pragma unroll
  for (int i = 0; i < 4; ++i) {
#pragma unroll
    for (int q = 0; q < 4; ++q) {
      const int row = m0 + wm + i * 16 + r4 + q;
      if (row < R.n_src) {
        const int d = R.deg_out[row];
        const float s = rsqrtf((float)(d > 1 ? d : 1));
#pragma unroll
        for (int j = 0; j < 4; ++j) {
          const int col = wn + j * 16 + l16;
          R.y[(size_t)row * OUT_F + col] = f2bf(acc[i][j][q] * s);
        }
      }
    }
  }
}

// ---------------- gather-aggregate + bias + relu (one wave per node, 16 lanes/row) ---
struct AggRel { const int* rowstart; const unsigned short* csr; const unsigned short* y; const float* b; };
struct AggType { AggRel r[4]; int n_rels; int n_nodes; float* out; };
struct AggParams { AggType t[4]; };

__global__ __launch_bounds__(256) void k_aggregate(AggParams p) {
  const AggType& T = p.t[blockIdx.y];
  const int node = blockIdx.x * 4 + (threadIdx.x >> 6);
  if (node >= T.n_nodes) return;
  const int lane = threadIdx.x & 63;
  const int quarter = lane >> 4;        // 0..3: interleaved edge streams
  const int c8 = (lane & 15) * 8;       // 8 columns per lane
  float ac[8] = {0,0,0,0,0,0,0,0};
  float bs[8] = {0,0,0,0,0,0,0,0};
#pragma unroll
  for (int rr = 0; rr < 4; ++rr) {
    if (rr < T.n_rels) {
      const AggRel R = T.r[rr];
      const int lo = R.rowstart[node];
      const int hi = R.rowstart[node + 1];
      float rx[8] = {0,0,0,0,0,0,0,0};
      int k = lo + quarter;
      for (; k + 12 < hi; k += 16) {   // 16 edges in flight per wave
        const int s0 = R.csr[k];
        const int s1 = R.csr[k + 4];
        const int s2 = R.csr[k + 8];
        const int s3 = R.csr[k + 12];
        const uint4 u0 = *(const uint4*)(R.y + (size_t)s0 * OUT_F + c8);
        const uint4 u1 = *(const uint4*)(R.y + (size_t)s1 * OUT_F + c8);
        const uint4 u2 = *(const uint4*)(R.y + (size_t)s2 * OUT_F + c8);
        const uint4 u3 = *(const uint4*)(R.y + (size_t)s3 * OUT_F + c8);
        add8(rx, u0); add8(rx, u1); add8(rx, u2); add8(rx, u3);
      }
      for (; k < hi; k += 4) {
        const int s0 = R.csr[k];
        const uint4 u0 = *(const uint4*)(R.y + (size_t)s0 * OUT_F + c8);
        add8(rx, u0);
      }
      const int deg = hi - lo;
      const float sc = rsqrtf((float)(deg > 1 ? deg : 1));
#pragma unroll
      for (int i = 0; i < 8; ++i) ac[i] = fmaf(rx[i], sc, ac[i]);
      const float4 b0 = *(const float4*)(R.b + c8);
      const float4 b1 = *(const float4*)(R.b + c8 + 4);
      bs[0] += b0.x; bs[1] += b0.y; bs[2] += b0.z; bs[3] += b0.w;
      bs[4] += b1.x; bs[5] += b1.y; bs[6] += b1.z; bs[7] += b1.w;
    }
  }
#pragma unroll
  for (int i = 0; i < 8; ++i) {
    ac[i] += __shfl_xor(ac[i], 16);
    ac[i] += __shfl_xor(ac[i], 32);
    ac[i] += bs[i];
    ac[i] = ac[i] > 0.f ? ac[i] : 0.f;
  }
  if (quarter == 0) {
    float* dst = T.out + (size_t)node * OUT_F + c8;
    float4 o0 = {ac[0], ac[1], ac[2], ac[3]};
    float4 o1 = {ac[4], ac[5], ac[6], ac[7]};
    *(float4*)dst = o0;
    *(float4*)(dst + 4) = o1;
  }
}

// ---------------- host ----------------
extern "C" void kernel_launch(void* const* d_in, const int* in_sizes, int n_in,
                              void* d_out, int out_size, void* d_ws, size_t ws_size,
                              hipStream_t stream) {
  const float* h[4];
  for (int i = 0; i < 4; ++i) h[i] = (const float*)d_in[i];
  const float* W[NREL]; const float* b[NREL];
  const int* src[NREL]; const int* dst[NREL];
  for (int r = 0; r < NREL; ++r) {
    W[r]   = (const float*)d_in[4 + 2 * r];
    b[r]   = (const float*)d_in[5 + 2 * r];
    src[r] = (const int*)d_in[24 + 2 * r];
    dst[r] = (const int*)d_in[25 + 2 * r];
  }
  float* out = (float*)d_out;

  int nblk[NREL];
  for (int r = 0; r < NREL; ++r) nblk[r] = (kNEdges[r] + CCHUNK - 1) / CCHUNK;

  char* ws = (char*)d_ws;
  size_t off = 0;
  auto alloc = [&](size_t bytes) -> char* {
    char* p = ws + off;
    off = (off + bytes + 255) & ~(size_t)255;
    return p;
  };
  int* degO[NREL];
  { char* base = alloc((size_t)92000 * 4); size_t o = 0;
    for (int r = 0; r < NREL; ++r) { degO[r] = (int*)(base + o); o += (size_t)kNSrc[r] * 4; } }
  int* totI[NREL];
  { char* base = alloc((size_t)92000 * 4); size_t o = 0;
    for (int r = 0; r < NREL; ++r) { totI[r] = (int*)(base + o); o += (size_t)kNDst[r] * 4; } }
  int* rowst[NREL];
  { char* base = alloc((size_t)(92000 + NREL) * 4); size_t o = 0;
    for (int r = 0; r < NREL; ++r) { rowst[r] = (int*)(base + o); o += (size_t)(kNDst[r] + 1) * 4; } }
  unsigned short* csr[NREL];
  { char* base = alloc((size_t)2500000 * 2); size_t o = 0;
    for (int r = 0; r < NREL; ++r) { csr[r] = (unsigned short*)(base + o); o += (size_t)kNEdges[r] * 2; } }
  unsigned short* Hsrc[NREL]; unsigned short* Hdst[NREL];
  { size_t tot = 0;
    for (int r = 0; r < NREL; ++r) tot += (size_t)nblk[r] * (kNSrc[r] + kNDst[r]);
    char* base = alloc(tot * 2); size_t o = 0;
    for (int r = 0; r < NREL; ++r) { Hsrc[r] = (unsigned short*)(base + o); o += (size_t)nblk[r] * kNSrc[r] * 2; }
    for (int r = 0; r < NREL; ++r) { Hdst[r] = (unsigned short*)(base + o); o += (size_t)nblk[r] * kNDst[r] * 2; } }
  unsigned short* y[NREL];
  { char* base = alloc((size_t)92000 * OUT_F * 2); size_t o = 0;
    for (int r = 0; r < NREL; ++r) { y[r] = (unsigned short*)(base + o); o += (size_t)kNSrc[r] * OUT_F * 2; } }
  unsigned short* WT[NREL];
  { char* base = alloc((size_t)NREL * IN_F * OUT_F * 2); size_t o = 0;
    for (int r = 0; r < NREL; ++r) { WT[r] = (unsigned short*)(base + o); o += (size_t)IN_F * OUT_F * 2; } }

  WtParams wp;
  for (int r = 0; r < NREL; ++r) { wp.W[r] = W[r]; wp.WT[r] = WT[r]; }
  k_wt<<<dim3(64, NREL), 256, 0, stream>>>(wp);

  int maxblk = 0;
  for (int r = 0; r < NREL; ++r) if (nblk[r] > maxblk) maxblk = nblk[r];

  CountParams cp;
  for (int r = 0; r < NREL; ++r) {
    cp.j[r]        = CountJob{src[r], Hsrc[r], kNEdges[r], kNSrc[r]};
    cp.j[NREL + r] = CountJob{dst[r], Hdst[r], kNEdges[r], kNDst[r]};
  }
  k_count<<<dim3(maxblk, 2 * NREL), 512, 0, stream>>>(cp);

  SumParams sp2;
  for (int r = 0; r < NREL; ++r) {
    sp2.j[r]        = SumJob{Hsrc[r], degO[r], kNSrc[r], nblk[r]};
    sp2.j[NREL + r] = SumJob{Hdst[r], totI[r], kNDst[r], nblk[r]};
  }
  k_sum<<<dim3((16000 + 255) / 256, 2 * NREL), 256, 0, stream>>>(sp2);

  ScanParams sp;
  for (int r = 0; r < NREL; ++r) sp.r[r] = ScanRel{totI[r], rowst[r], kNDst[r]};
  k_scan<<<NREL, 512, 0, stream>>>(sp);

  BasesParams bp;
  for (int r = 0; r < NREL; ++r) bp.j[r] = BasesJob{Hdst[r], kNDst[r], nblk[r]};
  k_bases<<<dim3((16000 + 255) / 256, NREL), 256, 0, stream>>>(bp);

  PlaceParams pp;
  for (int r = 0; r < NREL; ++r)
    pp.j[r] = PlaceJob{src[r], dst[r], Hdst[r], rowst[r], csr[r], kNEdges[r], kNDst[r]};
  k_place<<<dim3(maxblk, NREL), 512, 0, stream>>>(pp);

  GemmParams gp;
  for (int r = 0; r < NREL; ++r) gp.r[r] = GemmRel{h[kRelSrcType[r]], WT[r], y[r], degO[r], kNSrc[r]};
  k_gemm<<<dim3(NREL, (16000 + 127) / 128), 256, 0, stream>>>(gp);

  AggParams ap;
  for (int ti = 0; ti < 4; ++ti) {
    AggType& T = ap.t[ti];
    T.n_nodes = kNNodes[ti];
    T.n_rels = kNDstRels[ti];
    T.out = out + kOutOff[ti];
    for (int j = 0; j < 4; ++j) {
      int r = kDstRels[ti][j];
      if (r < 0) r = kDstRels[ti][0];
      T.r[j] = AggRel{rowst[r], csr[r], y[r], b[r]};
    }
  }
  k_aggregate<<<dim3((16000 + 3) / 4, 4), 256, 0, stream>>>(ap);
}

// Round 6
// 199.814 us; speedup vs baseline: 1.1180x; 1.1180x over previous
//
#include <hip/hip_runtime.h>
#include <cstddef>
#include <cstdint>

#define IN_F 512
#define OUT_F 128
#define NREL 10
#define MAXBINS 16000
#define CCHUNK 32768

typedef __attribute__((ext_vector_type(8))) short short8;
typedef __attribute__((ext_vector_type(4))) float f32x4;

static const int kNSrc[NREL]   = {8000,16000,8000,16000,8000,4000,8000,4000,16000,4000};
static const int kNDst[NREL]   = {8000,16000,16000,8000,4000,8000,4000,8000,4000,16000};
static const int kNEdges[NREL] = {200000,800000,400000,400000,100000,100000,100000,100000,150000,150000};
static const int kRelSrcType[NREL] = {0,1,0,1,0,2,0,3,1,2};
static const int kNNodes[4] = {8000,16000,4000,4000};
static const size_t kOutOff[4] = {0, 8000ull*OUT_F, 24000ull*OUT_F, 28000ull*OUT_F};
static const int kDstRels[4][4] = {{0,3,5,7},{1,2,9,-1},{4,8,-1,-1},{6,-1,-1,-1}};
static const int kNDstRels[4] = {4,3,2,1};

__device__ __forceinline__ unsigned short f2bf(float f) {
  union { float f; unsigned u; } v; v.f = f;
  unsigned r = v.u + 0x7fffu + ((v.u >> 16) & 1u);
  return (unsigned short)(r >> 16);
}
__device__ __forceinline__ void add8(float* a, uint4 u) {
  union { unsigned u; float f; } t;
  t.u = u.x << 16;        a[0] += t.f;
  t.u = u.x & 0xffff0000; a[1] += t.f;
  t.u = u.y << 16;        a[2] += t.f;
  t.u = u.y & 0xffff0000; a[3] += t.f;
  t.u = u.z << 16;        a[4] += t.f;
  t.u = u.z & 0xffff0000; a[5] += t.f;
  t.u = u.w << 16;        a[6] += t.f;
  t.u = u.w & 0xffff0000; a[7] += t.f;
}

// ---------------- per-chunk LDS histogram -> coalesced u16 H rows ---------------------
struct CountJob { const int* idx; unsigned short* H; int n_edges; int nbins; };
struct CountParams { CountJob j[2 * NREL]; };

__global__ __launch_bounds__(1024) void k_count(CountParams p) {
  CountJob J = p.j[blockIdx.y];
  const int e0 = blockIdx.x * CCHUNK;
  if (e0 >= J.n_edges) return;
  __shared__ int lb[MAXBINS];
  const int t = threadIdx.x;
  for (int d = t; d < J.nbins; d += 1024) lb[d] = 0;
  __syncthreads();
  const int eend = (e0 + CCHUNK < J.n_edges) ? e0 + CCHUNK : J.n_edges;
  for (int e = e0 + t; e < eend; e += 1024) atomicAdd(&lb[J.idx[e]], 1);
  __syncthreads();
  unsigned short* Hrow = J.H + (size_t)blockIdx.x * J.nbins;
  for (int d = t; d < J.nbins; d += 1024) Hrow[d] = (unsigned short)lb[d];
}

// ---------------- column-sum of H -> totals, coalesced --------------------------------
struct SumJob { const unsigned short* H; int* tot; int nbins; int nblocks; };
struct SumParams { SumJob j[2 * NREL]; };

__global__ __launch_bounds__(256) void k_sum(SumParams p) {
  SumJob J = p.j[blockIdx.y];
  const int bin = blockIdx.x * 256 + threadIdx.x;
  if (bin >= J.nbins) return;
  int s = 0;
  for (int b = 0; b < J.nblocks; ++b) s += J.H[(size_t)b * J.nbins + bin];
  J.tot[bin] = s;
}

// ---------------- exclusive scan (one 512-thread block per relation, n<=16384) -------
struct ScanRel { const int* tot; int* rowstart; int n; };
struct ScanParams { ScanRel r[NREL]; };

__global__ __launch_bounds__(512) void k_scan(ScanParams p) {
  ScanRel R = p.r[blockIdx.x];
  const int t = threadIdx.x;
  const int lane = t & 63, wv = t >> 6;
  const int base = t * 32;
  int v[32];
  int s = 0;
#pragma unroll
  for (int i = 0; i < 32; ++i) {
    int e = base + i;
    int x = (e < R.n) ? R.tot[e] : 0;
    v[i] = s; s += x;
  }
  int inc = s;
#pragma unroll
  for (int off = 1; off < 64; off <<= 1) {
    int u = __shfl_up(inc, off);
    if (lane >= off) inc += u;
  }
  __shared__ int wsum[8];
  if (lane == 63) wsum[wv] = inc;
  __syncthreads();
  int carry = 0, total = 0;
#pragma unroll
  for (int w = 0; w < 8; ++w) {
    int x = wsum[w];
    if (w < wv) carry += x;
    total += x;
  }
  const int tb = carry + (inc - s);
#pragma unroll
  for (int i = 0; i < 32; ++i) {
    int e = base + i;
    if (e < R.n) R.rowstart[e] = tb + v[i];
  }
  if (t == 0) R.rowstart[R.n] = total;
}

// ---------------- per-bin exclusive prefix over chunk-blocks (in place, u16) ---------
struct BasesJob { unsigned short* H; int nbins; int nblocks; };
struct BasesParams { BasesJob j[NREL]; };

__global__ __launch_bounds__(256) void k_bases(BasesParams p) {
  BasesJob J = p.j[blockIdx.y];
  const int bin = blockIdx.x * 256 + threadIdx.x;
  if (bin >= J.nbins) return;
  int run = 0;
  for (int b = 0; b < J.nblocks; ++b) {
    const size_t o = (size_t)b * J.nbins + bin;
    const int c = J.H[o];
    J.H[o] = (unsigned short)run;
    run += c;
  }
}

// ---------------- place edges via LDS cursors (no global atomics, u16 csr) -----------
struct PlaceJob { const int* src; const int* dst; const unsigned short* Hpre; const int* rowstart;
                  unsigned short* csr; int n_edges; int nbins; };
struct PlaceParams { PlaceJob j[NREL]; };

__global__ __launch_bounds__(1024) void k_place(PlaceParams p) {
  PlaceJob J = p.j[blockIdx.y];
  const int e0 = blockIdx.x * CCHUNK;
  if (e0 >= J.n_edges) return;
  __shared__ int lb[MAXBINS];
  const int t = threadIdx.x;
  const unsigned short* Hrow = J.Hpre + (size_t)blockIdx.x * J.nbins;
  for (int d = t; d < J.nbins; d += 1024) lb[d] = J.rowstart[d] + (int)Hrow[d];
  __syncthreads();
  const int eend = (e0 + CCHUNK < J.n_edges) ? e0 + CCHUNK : J.n_edges;
  for (int e = e0 + t; e < eend; e += 1024) {
    const int d = J.dst[e];
    const int pos = atomicAdd(&lb[d], 1);
    J.csr[pos] = (unsigned short)J.src[e];
  }
}

// ---------------- W -> W^T bf16 ----------------
struct WtParams { const float* W[NREL]; unsigned short* WT[NREL]; };

__global__ __launch_bounds__(256) void k_wt(WtParams p) {
  const int r = blockIdx.y;
  const int g = blockIdx.x * 256 + threadIdx.x;  // 0..16383
  const int k = g >> 5;
  const int n0 = (g & 31) * 4;
  const float4 w = *(const float4*)(p.W[r] + (size_t)k * OUT_F + n0);
  unsigned short* WT = p.WT[r];
  WT[(size_t)(n0 + 0) * IN_F + k] = f2bf(w.x);
  WT[(size_t)(n0 + 1) * IN_F + k] = f2bf(w.y);
  WT[(size_t)(n0 + 2) * IN_F + k] = f2bf(w.z);
  WT[(size_t)(n0 + 3) * IN_F + k] = f2bf(w.w);
}

// ---------------- y_r = (h @ W_r) * deg_out^-1/2, bf16 MFMA ----------------
// 723 jobs = (type,rowtile,rel) enumerated so same-A jobs are consecutive; bijective
// XCD swizzle (m204) keeps consecutive jobs on one XCD's L2.
struct GemmRel { const float* h; const unsigned short* WT; unsigned short* y; const int* deg_out; int n_src; };
struct GemmParams { GemmRel r[NREL]; };

#define GEMM_JOBS 723

__global__ __launch_bounds__(256) void k_gemm(GemmParams p) {
  // --- bijective XCD swizzle: orig -> jobid ---
  const int orig = blockIdx.x;
  const int xcd = orig & 7;
  const int i8 = orig >> 3;
  const int q = GEMM_JOBS / 8, rm = GEMM_JOBS % 8;   // 90, 3
  const int g = (xcd < rm ? xcd * (q + 1) : rm * (q + 1) + (xcd - rm) * q) + i8;
  // --- decode jobid -> (rel, rowtile) ---
  static const int dr[4] = {0, 2, 4, 6};
  static const int pr[3] = {1, 3, 8};
  static const int xr[2] = {5, 9};
  int rel, tile;
  if (g < 252)      { rel = dr[g & 3]; tile = g >> 2; }          // drug: 63 tiles x 4 rels
  else if (g < 627) { int u = g - 252; rel = pr[u % 3]; tile = u / 3; }  // protein: 125 x 3
  else if (g < 691) { int u = g - 627; rel = xr[u & 1]; tile = u >> 1; } // disease: 32 x 2
  else              { rel = 7; tile = g - 691; }                  // sideeffect: 32 x 1

  GemmRel R = p.r[rel];
  const int m0 = tile * 128;

  __shared__ unsigned short As[2][128][40];
  __shared__ unsigned short Bs[2][128][40];
  const int t = threadIdx.x;
  const int lane = t & 63, wid = t >> 6;
  const int wm = (wid >> 1) * 64, wn = (wid & 1) * 64;
  const int l16 = lane & 15, lk = (lane >> 4) * 8;
  const int srow = t >> 1;           // 0..127
  const int sk = (t & 1) * 16;       // element offset 0 or 16
  const int grA = m0 + srow;
  const bool avalid = grA < R.n_src;
  const float* aptr = R.h + (size_t)(avalid ? grA : 0) * IN_F + sk;
  const unsigned short* bptr = R.WT + (size_t)srow * IN_F + sk;

  f32x4 acc[4][4];
#pragma unroll
  for (int i = 0; i < 4; ++i)
#pragma unroll
    for (int j = 0; j < 4; ++j) acc[i][j] = (f32x4){0.f, 0.f, 0.f, 0.f};

  float4 a0, a1, a2, a3;
  uint4 b0, b1;
  auto gload = [&](int k0) {
    if (avalid) {
      a0 = *(const float4*)(aptr + k0);
      a1 = *(const float4*)(aptr + k0 + 4);
      a2 = *(const float4*)(aptr + k0 + 8);
      a3 = *(const float4*)(aptr + k0 + 12);
    } else {
      a0 = a1 = a2 = a3 = make_float4(0.f, 0.f, 0.f, 0.f);
    }
    b0 = *(const uint4*)(bptr + k0);
    b1 = *(const uint4*)(bptr + k0 + 8);
  };
  auto stage = [&](int buf) {
    uint4 A0, A1;
    A0.x = (unsigned)f2bf(a0.x) | ((unsigned)f2bf(a0.y) << 16);
    A0.y = (unsigned)f2bf(a0.z) | ((unsigned)f2bf(a0.w) << 16);
    A0.z = (unsigned)f2bf(a1.x) | ((unsigned)f2bf(a1.y) << 16);
    A0.w = (unsigned)f2bf(a1.z) | ((unsigned)f2bf(a1.w) << 16);
    A1.x = (unsigned)f2bf(a2.x) | ((unsigned)f2bf(a2.y) << 16);
    A1.y = (unsigned)f2bf(a2.z) | ((unsigned)f2bf(a2.w) << 16);
    A1.z = (unsigned)f2bf(a3.x) | ((unsigned)f2bf(a3.y) << 16);
    A1.w = (unsigned)f2bf(a3.z) | ((unsigned)f2bf(a3.w) << 16);
    *(uint4*)&As[buf][srow][sk] = A0;
    *(uint4*)&As[buf][srow][sk + 8] = A1;
    *(uint4*)&Bs[buf][srow][sk] = b0;
    *(uint4*)&Bs[buf][srow][sk + 8] = b1;
  };

  gload(0);
  stage(0);
  __syncthreads();
  int buf = 0;
#pragma unroll 1
  for (int s = 0; s < 16; ++s) {
    if (s < 15) gload((s + 1) * 32);   // issue next-tile loads before compute
    short8 af[4], bfr[4];
#pragma unroll
    for (int f = 0; f < 4; ++f) af[f] = *(const short8*)&As[buf][wm + f * 16 + l16][lk];
#pragma unroll
    for (int f = 0; f < 4; ++f) bfr[f] = *(const short8*)&Bs[buf][wn + f * 16 + l16][lk];
#pragma unroll
    for (int i = 0; i < 4; ++i)
#pragma unroll
      for (int j = 0; j < 4; ++j)
        acc[i][j] = __builtin_amdgcn_mfma_f32_16x16x32_bf16(af[i], bfr[j], acc[i][j], 0, 0, 0);
    if (s < 15) stage(buf ^ 1);        // waits vmcnt, writes other buffer
    __syncthreads();
    buf ^= 1;
  }

  const int r4 = (lane >> 4) * 4;  // C/D: col=lane&15, row=(lane>>4)*4+q
#pragma unroll
  for (int i = 0; i < 4; ++i) {
#pragma unroll
    for (int qq = 0; qq < 4; ++qq) {
      const int row = m0 + wm + i * 16 + r4 + qq;
      if (row < R.n_src) {
        const int d = R.deg_out[row];
        const float sc = rsqrtf((float)(d > 1 ? d : 1));
#pragma unroll
        for (int j = 0; j < 4; ++j) {
          const int col = wn + j * 16 + l16;
          R.y[(size_t)row * OUT_F + col] = f2bf(acc[i][j][qq] * sc);
        }
      }
    }
  }
}

// ---------------- gather-aggregate + bias + relu (one wave per node, 16 lanes/row) ---
struct AggRel { const int* rowstart; const unsigned short* csr; const unsigned short* y; const float* b; };
struct AggType { AggRel r[4]; int n_rels; int n_nodes; float* out; };
struct AggParams { AggType t[4]; };

__global__ __launch_bounds__(256) void k_aggregate(AggParams p) {
  const AggType& T = p.t[blockIdx.y];
  const int node = blockIdx.x * 4 + (threadIdx.x >> 6);
  if (node >= T.n_nodes) return;
  const int lane = threadIdx.x & 63;
  const int quarter = lane >> 4;        // 0..3: interleaved edge streams
  const int c8 = (lane & 15) * 8;       // 8 columns per lane
  float ac[8] = {0,0,0,0,0,0,0,0};
  float bs[8] = {0,0,0,0,0,0,0,0};
#pragma unroll
  for (int rr = 0; rr < 4; ++rr) {
    if (rr < T.n_rels) {
      const AggRel R = T.r[rr];
      const int lo = R.rowstart[node];
      const int hi = R.rowstart[node + 1];
      float rx[8] = {0,0,0,0,0,0,0,0};
      int k = lo + quarter;
      for (; k + 12 < hi; k += 16) {   // 16 edges in flight per wave
        const int s0 = R.csr[k];
        const int s1 = R.csr[k + 4];
        const int s2 = R.csr[k + 8];
        const int s3 = R.csr[k + 12];
        const uint4 u0 = *(const uint4*)(R.y + (size_t)s0 * OUT_F + c8);
        const uint4 u1 = *(const uint4*)(R.y + (size_t)s1 * OUT_F + c8);
        const uint4 u2 = *(const uint4*)(R.y + (size_t)s2 * OUT_F + c8);
        const uint4 u3 = *(const uint4*)(R.y + (size_t)s3 * OUT_F + c8);
        add8(rx, u0); add8(rx, u1); add8(rx, u2); add8(rx, u3);
      }
      for (; k < hi; k += 4) {
        const int s0 = R.csr[k];
        const uint4 u0 = *(const uint4*)(R.y + (size_t)s0 * OUT_F + c8);
        add8(rx, u0);
      }
      const int deg = hi - lo;
      const float sc = rsqrtf((float)(deg > 1 ? deg : 1));
#pragma unroll
      for (int i = 0; i < 8; ++i) ac[i] = fmaf(rx[i], sc, ac[i]);
      const float4 b0 = *(const float4*)(R.b + c8);
      const float4 b1 = *(const float4*)(R.b + c8 + 4);
      bs[0] += b0.x; bs[1] += b0.y; bs[2] += b0.z; bs[3] += b0.w;
      bs[4] += b1.x; bs[5] += b1.y; bs[6] += b1.z; bs[7] += b1.w;
    }
  }
#pragma unroll
  for (int i = 0; i < 8; ++i) {
    ac[i] += __shfl_xor(ac[i], 16);
    ac[i] += __shfl_xor(ac[i], 32);
    ac[i] += bs[i];
    ac[i] = ac[i] > 0.f ? ac[i] : 0.f;
  }
  if (quarter == 0) {
    float* dst = T.out + (size_t)node * OUT_F + c8;
    float4 o0 = {ac[0], ac[1], ac[2], ac[3]};
    float4 o1 = {ac[4], ac[5], ac[6], ac[7]};
    *(float4*)dst = o0;
    *(float4*)(dst + 4) = o1;
  }
}

// ---------------- host ----------------
extern "C" void kernel_launch(void* const* d_in, const int* in_sizes, int n_in,
                              void* d_out, int out_size, void* d_ws, size_t ws_size,
                              hipStream_t stream) {
  const float* h[4];
  for (int i = 0; i < 4; ++i) h[i] = (const float*)d_in[i];
  const float* W[NREL]; const float* b[NREL];
  const int* src[NREL]; const int* dst[NREL];
  for (int r = 0; r < NREL; ++r) {
    W[r]   = (const float*)d_in[4 + 2 * r];
    b[r]   = (const float*)d_in[5 + 2 * r];
    src[r] = (const int*)d_in[24 + 2 * r];
    dst[r] = (const int*)d_in[25 + 2 * r];
  }
  float* out = (float*)d_out;

  int nblk[NREL];
  for (int r = 0; r < NREL; ++r) nblk[r] = (kNEdges[r] + CCHUNK - 1) / CCHUNK;

  char* ws = (char*)d_ws;
  size_t off = 0;
  auto alloc = [&](size_t bytes) -> char* {
    char* p = ws + off;
    off = (off + bytes + 255) & ~(size_t)255;
    return p;
  };
  int* degO[NREL];
  { char* base = alloc((size_t)92000 * 4); size_t o = 0;
    for (int r = 0; r < NREL; ++r) { degO[r] = (int*)(base + o); o += (size_t)kNSrc[r] * 4; } }
  int* totI[NREL];
  { char* base = alloc((size_t)92000 * 4); size_t o = 0;
    for (int r = 0; r < NREL; ++r) { totI[r] = (int*)(base + o); o += (size_t)kNDst[r] * 4; } }
  int* rowst[NREL];
  { char* base = alloc((size_t)(92000 + NREL) * 4); size_t o = 0;
    for (int r = 0; r < NREL; ++r) { rowst[r] = (int*)(base + o); o += (size_t)(kNDst[r] + 1) * 4; } }
  unsigned short* csr[NREL];
  { char* base = alloc((size_t)2500000 * 2); size_t o = 0;
    for (int r = 0; r < NREL; ++r) { csr[r] = (unsigned short*)(base + o); o += (size_t)kNEdges[r] * 2; } }
  unsigned short* Hsrc[NREL]; unsigned short* Hdst[NREL];
  { size_t tot = 0;
    for (int r = 0; r < NREL; ++r) tot += (size_t)nblk[r] * (kNSrc[r] + kNDst[r]);
    char* base = alloc(tot * 2); size_t o = 0;
    for (int r = 0; r < NREL; ++r) { Hsrc[r] = (unsigned short*)(base + o); o += (size_t)nblk[r] * kNSrc[r] * 2; }
    for (int r = 0; r < NREL; ++r) { Hdst[r] = (unsigned short*)(base + o); o += (size_t)nblk[r] * kNDst[r] * 2; } }
  unsigned short* y[NREL];
  { char* base = alloc((size_t)92000 * OUT_F * 2); size_t o = 0;
    for (int r = 0; r < NREL; ++r) { y[r] = (unsigned short*)(base + o); o += (size_t)kNSrc[r] * OUT_F * 2; } }
  unsigned short* WT[NREL];
  { char* base = alloc((size_t)NREL * IN_F * OUT_F * 2); size_t o = 0;
    for (int r = 0; r < NREL; ++r) { WT[r] = (unsigned short*)(base + o); o += (size_t)IN_F * OUT_F * 2; } }

  WtParams wp;
  for (int r = 0; r < NREL; ++r) { wp.W[r] = W[r]; wp.WT[r] = WT[r]; }
  k_wt<<<dim3(64, NREL), 256, 0, stream>>>(wp);

  int maxblk = 0;
  for (int r = 0; r < NREL; ++r) if (nblk[r] > maxblk) maxblk = nblk[r];

  CountParams cp;
  for (int r = 0; r < NREL; ++r) {
    cp.j[r]        = CountJob{src[r], Hsrc[r], kNEdges[r], kNSrc[r]};
    cp.j[NREL + r] = CountJob{dst[r], Hdst[r], kNEdges[r], kNDst[r]};
  }
  k_count<<<dim3(maxblk, 2 * NREL), 1024, 0, stream>>>(cp);

  SumParams sp2;
  for (int r = 0; r < NREL; ++r) {
    sp2.j[r]        = SumJob{Hsrc[r], degO[r], kNSrc[r], nblk[r]};
    sp2.j[NREL + r] = SumJob{Hdst[r], totI[r], kNDst[r], nblk[r]};
  }
  k_sum<<<dim3((16000 + 255) / 256, 2 * NREL), 256, 0, stream>>>(sp2);

  ScanParams sp;
  for (int r = 0; r < NREL; ++r) sp.r[r] = ScanRel{totI[r], rowst[r], kNDst[r]};
  k_scan<<<NREL, 512, 0, stream>>>(sp);

  BasesParams bp;
  for (int r = 0; r < NREL; ++r) bp.j[r] = BasesJob{Hdst[r], kNDst[r], nblk[r]};
  k_bases<<<dim3((16000 + 255) / 256, NREL), 256, 0, stream>>>(bp);

  PlaceParams pp;
  for (int r = 0; r < NREL; ++r)
    pp.j[r] = PlaceJob{src[r], dst[r], Hdst[r], rowst[r], csr[r], kNEdges[r], kNDst[r]};
  k_place<<<dim3(maxblk, NREL), 1024, 0, stream>>>(pp);

  GemmParams gp;
  for (int r = 0; r < NREL; ++r) gp.r[r] = GemmRel{h[kRelSrcType[r]], WT[r], y[r], degO[r], kNSrc[r]};
  k_gemm<<<GEMM_JOBS, 256, 0, stream>>>(gp);

  AggParams ap;
  for (int ti = 0; ti < 4; ++ti) {
    AggType& T = ap.t[ti];
    T.n_nodes = kNNodes[ti];
    T.n_rels = kNDstRels[ti];
    T.out = out + kOutOff[ti];
    for (int j = 0; j < 4; ++j) {
      int r = kDstRels[ti][j];
      if (r < 0) r = kDstRels[ti][0];
      T.r[j] = AggRel{rowst[r], csr[r], y[r], b[r]};
    }
  }
  k_aggregate<<<dim3((16000 + 3) / 4, 4), 256, 0, stream>>>(ap);
}